// Round 6
// baseline (616.006 us; speedup 1.0000x reference)
//
#include <hip/hip_runtime.h>

// ---- problem dims ----
#define IN_DIM 8193
#define OUT_DIM 4097
#define NB 1024
// padded dims
#define MP1 8320
#define KP1 8256
#define MP2 4224
#define KP2 4160

typedef __attribute__((ext_vector_type(8))) short short8;
typedef __attribute__((ext_vector_type(4))) float f32x4;

__device__ __forceinline__ unsigned short f2bf(float f) {
  unsigned int u = __float_as_uint(f);
  u = (u + 0x7fffu + ((u >> 16) & 1u)) >> 16;  // RNE
  return (unsigned short)u;
}

// ---- transpose + convert: src (K x N) f32 -> dst (N x Kp) bf16, zero pad ----
__global__ __launch_bounds__(256) void transpose_cvt_kernel(
    const float* __restrict__ src, unsigned short* __restrict__ dst,
    int K, int N, int Kp) {
  __shared__ float tl[32][33];
  const int ntk = Kp >> 5;
  int bx = blockIdx.x % ntk;
  int by = blockIdx.x / ntk;
  int k0 = bx * 32, n0 = by * 32;
  int tx = threadIdx.x & 31, ty = threadIdx.x >> 5;
#pragma unroll
  for (int i = 0; i < 4; ++i) {
    int k = k0 + ty + i * 8;
    tl[ty + i * 8][tx] = (k < K) ? src[(size_t)k * N + n0 + tx] : 0.f;
  }
  __syncthreads();
#pragma unroll
  for (int i = 0; i < 4; ++i) {
    int n = n0 + ty + i * 8;
    dst[(size_t)n * Kp + k0 + tx] = f2bf(tl[tx][ty + i * 8]);
  }
}

// ---- GEMM with fused A-conversion:
//   Cpart(sp) (Mout x NB) = Af(:, ksplit) * Bt(:, ksplit)^T
// Af is the ORIGINAL f32 matrix (Mout x Kact, unpadded). A-tile staging is
// reg-staged: 16 contiguous f32/thread -> RNE bf16 -> 2x ds_write_b128 at the
// XOR-swizzled LDS address (reg-staging lifts the gload_lds linear-dest
// constraint, so swizzle-on-write is legal). B-side (pre-converted bf16,
// zero-padded to NB x Kp) stays global_load_lds width-16.
// Structure: R4-proven 2-barrier, 128x128 tile, BK=64, 8 waves (2Mx4N).
// Split-K: grid = nsplit * nbm * 8; partial outputs stride Mout*NB.
// XCD-aware remap: the 8 bn-blocks of one bm share an A-panel -> same XCD L2.
__global__ __launch_bounds__(512, 4) void gemm_f32a(
    const float* __restrict__ Af,
    const unsigned short* __restrict__ Bt,
    float* __restrict__ C,
    int Kp, int Mout, int Kact, int nbm, int nsplit) {
  __shared__ unsigned short As[128 * 64];
  __shared__ unsigned short Bs[128 * 64];
  const int tid = threadIdx.x;
  const int wid = tid >> 6;
  const int lane = tid & 63;
  const int bps = nbm * 8;             // nbn = 8 (N=1024, BN=128)
  const int sp = blockIdx.x / bps;
  const int j = blockIdx.x - sp * bps;
  // XCD-aware bijective remap (same-bm blocks -> same XCD L2)
  const int full = (nbm & ~7) << 3;
  int bm, bn;
  if (j < full) {
    bm = ((j >> 6) << 3) + (j & 7);
    bn = (j >> 3) & 7;
  } else {
    const int r = j - full;
    bm = (full >> 3) + (r >> 3);
    bn = r & 7;
  }
  const int m0 = bm << 7, n0 = bn << 7;
  const int wm = (wid >> 2) << 6;   // 0 or 64
  const int wn = (wid & 3) << 5;    // 0,32,64,96

  // K-tile range for this split
  const int nk = Kp >> 6;
  const int q = nk / nsplit, rr = nk - q * nsplit;
  const int kt0 = sp * q + (sp < rr ? sp : rr);
  const int ktn = q + (sp < rr ? 1 : 0);

  float* Cp = C + (size_t)sp * Mout * NB;

  // A-staging geometry: thread -> (row, granule-pair)
  const int arow = tid >> 2;           // 0..127
  const int gp = (tid & 3) << 1;       // 0,2,4,6 (granule pair base)
  const bool rok = (m0 + arow) < Mout;
  const float* arow_ptr = Af + (size_t)(m0 + arow) * Kact;

  f32x4 acc[4][2] = {};

  for (int kt = kt0; kt < kt0 + ktn; ++kt) {
    const int k0 = kt << 6;
    // ---- A: 16 contiguous f32 -> regs (issued first, longest dep chain) ----
    const int gk = k0 + gp * 8;
    float fv[16];
    if (rok && (gk + 16 <= Kact)) {
      const float* s4 = arow_ptr + gk;
#pragma unroll
      for (int jj = 0; jj < 16; ++jj) fv[jj] = s4[jj];
    } else {
#pragma unroll
      for (int jj = 0; jj < 16; ++jj)
        fv[jj] = (rok && (gk + jj < Kact)) ? arow_ptr[gk + jj] : 0.f;
    }
    // ---- B: async global_load_lds (bf16, zero-padded source) ----
#pragma unroll
    for (int i = 0; i < 2; ++i) {
      const int s = i * 512 + tid;
      const int brow = s >> 3;
      const int gl = (s & 7) ^ (brow & 7);
      const unsigned short* gb = Bt + (size_t)(n0 + brow) * Kp + (k0 + gl * 8);
      unsigned short* lb = Bs + (size_t)(i * 512 + wid * 64) * 8;
      __builtin_amdgcn_global_load_lds(
          (const __attribute__((address_space(1))) void*)gb,
          (__attribute__((address_space(3))) void*)lb, 16, 0, 0);
    }
    // ---- A: convert + swizzled ds_write (waits on the f32 loads) ----
#pragma unroll
    for (int g = 0; g < 2; ++g) {
      const int p = (gp + g) ^ (arow & 7);
      short8 v;
#pragma unroll
      for (int jj = 0; jj < 8; ++jj) v[jj] = (short)f2bf(fv[g * 8 + jj]);
      *reinterpret_cast<short8*>(As + arow * 64 + p * 8) = v;
    }
    __syncthreads();
    // ---- compute (identical to R4) ----
#pragma unroll
    for (int kk = 0; kk < 2; ++kk) {
      short8 af[4], bfr[2];
#pragma unroll
      for (int mf = 0; mf < 4; ++mf) {
        const int row = wm + mf * 16 + (lane & 15);
        const int g = (kk * 4 + (lane >> 4)) ^ (row & 7);
        af[mf] = *reinterpret_cast<const short8*>(As + row * 64 + g * 8);
      }
#pragma unroll
      for (int nf = 0; nf < 2; ++nf) {
        const int row = wn + nf * 16 + (lane & 15);
        const int g = (kk * 4 + (lane >> 4)) ^ (row & 7);
        bfr[nf] = *reinterpret_cast<const short8*>(Bs + row * 64 + g * 8);
      }
#pragma unroll
      for (int mf = 0; mf < 4; ++mf)
#pragma unroll
        for (int nf = 0; nf < 2; ++nf)
          asm volatile("v_mfma_f32_16x16x32_bf16 %0, %1, %2, %0"
                       : "+v"(acc[mf][nf])
                       : "v"(af[mf]), "v"(bfr[nf]));
    }
    __syncthreads();
  }
  // epilogue: C/D layout col=lane&15, row=(lane>>4)*4+reg  [m89-verified]
#pragma unroll
  for (int mf = 0; mf < 4; ++mf) {
    const int rbase = m0 + wm + mf * 16 + (lane >> 4) * 4;
#pragma unroll
    for (int nf = 0; nf < 2; ++nf) {
      const int col = n0 + wn + nf * 16 + (lane & 15);
#pragma unroll
      for (int r = 0; r < 4; ++r) {
        const int row = rbase + r;
        if (row < Mout) Cp[(size_t)row * NB + col] = acc[mf][nf][r];
      }
    }
  }
}

// ---- conv: z = za+zb (8193 x 1024) f32 -> tT (1024 x KP2) bf16 ----
__global__ __launch_bounds__(256) void conv_tT_kernel(
    const float* __restrict__ za, const float* __restrict__ zb,
    const float* __restrict__ w, const float* __restrict__ bias,
    unsigned short* __restrict__ tT) {
  const int gid = blockIdx.x * 256 + threadIdx.x;
  const int n = gid & 1023;
  const int rg = gid >> 10;  // 0..519
  const int r0 = rg << 3;
  const size_t homoff = (size_t)8192 * 1024 + n;
  const float hom = za[homoff] + zb[homoff];
  unsigned short o[8];
  if (r0 >= 4096) {
#pragma unroll
    for (int j = 0; j < 8; ++j) o[j] = f2bf((r0 + j == 4096) ? hom : 0.f);
  } else {
    const int co = r0 >> 8;
    const int uo = (r0 >> 4) & 15;
    const int vo0 = r0 & 15;  // 0 or 8
    float acc[8];
    const float bb = bias[co];
#pragma unroll
    for (int j = 0; j < 8; ++j) acc[j] = bb * hom;
    for (int ci = 0; ci < 8; ++ci) {
#pragma unroll
      for (int kh = 0; kh < 3; ++kh) {
        const int u = uo * 2 + kh;
        if (u >= 32) continue;
        const size_t zoff = (size_t)(ci * 1024 + u * 32) * 1024 + n;
#pragma unroll
        for (int kw = 0; kw < 3; ++kw) {
          const float wv = w[((co * 8 + ci) * 3 + kh) * 3 + kw];
#pragma unroll
          for (int j = 0; j < 8; ++j) {
            const int v = (vo0 + j) * 2 + kw;
            if (v < 32) {
              const size_t e = zoff + (size_t)v * 1024;
              acc[j] += wv * (za[e] + zb[e]);
            }
          }
        }
      }
    }
#pragma unroll
    for (int j = 0; j < 8; ++j) o[j] = f2bf(acc[j]);
  }
  uint4 pv;
  pv.x = (unsigned)o[0] | ((unsigned)o[1] << 16);
  pv.y = (unsigned)o[2] | ((unsigned)o[3] << 16);
  pv.z = (unsigned)o[4] | ((unsigned)o[5] << 16);
  pv.w = (unsigned)o[6] | ((unsigned)o[7] << 16);
  *reinterpret_cast<uint4*>(tT + (size_t)n * KP2 + r0) = pv;
}

// ---- final sum of 4 split-K partials -> d_out ----
__global__ __launch_bounds__(256) void sum4_kernel(
    const float* __restrict__ p, float* __restrict__ out, int n4) {
  const int i = blockIdx.x * 256 + threadIdx.x;
  if (i >= n4) return;
  const size_t stride4 = (size_t)OUT_DIM * NB / 4;
  const float4* p4 = (const float4*)p;
  float4 a = p4[i];
  float4 b = p4[i + stride4];
  float4 c = p4[i + 2 * stride4];
  float4 d = p4[i + 3 * stride4];
  float4 r;
  r.x = (a.x + b.x) + (c.x + d.x);
  r.y = (a.y + b.y) + (c.y + d.y);
  r.z = (a.z + b.z) + (c.z + d.z);
  r.w = (a.w + b.w) + (c.w + d.w);
  reinterpret_cast<float4*>(out)[i] = r;
}

extern "C" void kernel_launch(void* const* d_in, const int* in_sizes, int n_in,
                              void* d_out, int out_size, void* d_ws, size_t ws_size,
                              hipStream_t stream) {
  const float* w    = (const float*)d_in[0];  // (16,8,3,3)
  const float* bias = (const float*)d_in[1];  // (16,)
  const float* A    = (const float*)d_in[2];  // (4097,4097)
  const float* Ainv = (const float*)d_in[3];  // (8193,8193)
  const float* x    = (const float*)d_in[4];  // (8193,1024)
  float* out = (float*)d_out;                 // (4097,1024)

  // Workspace (92.6 MB):
  //   xT_b 16.9 | z2/outp region 67.13 (outp is 8KB larger; region sized for
  //   outp; z2 aliases its start — z2 dead after conv, outp written by GEMM2
  //   after conv, stream-ordered) | tT_b 8.5
  char* ws = (char*)d_ws;
  unsigned short* xT_b = (unsigned short*)ws;
  float*          z2   = (float*)(ws + (size_t)NB * KP1 * 2);
  float*          outp = z2;
  unsigned short* tT_b = (unsigned short*)(ws + (size_t)NB * KP1 * 2
                                           + (size_t)4 * OUT_DIM * NB * 4);
  (void)ws_size; (void)in_sizes; (void)n_in; (void)out_size;

  // 1) x -> x^T padded bf16 (NB x KP1)
  transpose_cvt_kernel<<<(KP1 / 32) * (NB / 32), 256, 0, stream>>>(
      x, xT_b, IN_DIM, NB, KP1);
  // 2) z{a,b} = Ainv @ x  (fused-cvt GEMM, split-K=2 -> 1040 blocks)
  gemm_f32a<<<2 * 65 * 8, 512, 0, stream>>>(
      Ainv, xT_b, z2, KP1, IN_DIM, IN_DIM, 65, 2);
  // 3) t^T = conv(za+zb)  (incl. hom row + zero pad)
  conv_tT_kernel<<<(520 * 1024) / 256, 256, 0, stream>>>(
      z2, z2 + (size_t)IN_DIM * NB, w, bias, tT_b);
  // 4) outp[0..3] = A @ t  (fused-cvt GEMM, split-K=4 -> 1056 blocks)
  gemm_f32a<<<4 * 33 * 8, 512, 0, stream>>>(
      A, tT_b, outp, KP2, OUT_DIM, OUT_DIM, 33, 4);
  // 5) out = sum of partials
  const int n4 = OUT_DIM * NB / 4;
  sum4_kernel<<<(n4 + 255) / 256, 256, 0, stream>>>(outp, out, n4);
}

// Round 7
// 439.846 us; speedup vs baseline: 1.4005x; 1.4005x over previous
//
#include <hip/hip_runtime.h>

// ---- problem dims ----
#define IN_DIM 8193
#define OUT_DIM 4097
#define NB 1024
// padded dims (M -> mult of 256, K -> mult of 64)
#define MP1 8448   // 33 * 256
#define KP1 8256   // 129 * 64
#define MP2 4352   // 17 * 256
#define KP2 4160   // 65 * 64

typedef __attribute__((ext_vector_type(8))) short short8;
typedef __attribute__((ext_vector_type(4))) float f32x4;

__device__ __forceinline__ unsigned short f2bf(float f) {
  unsigned int u = __float_as_uint(f);
  u = (u + 0x7fffu + ((u >> 16) & 1u)) >> 16;  // RNE
  return (unsigned short)u;
}

// ---- pad + f32->bf16 convert (row-major -> row-major padded) ----
__global__ __launch_bounds__(256) void cvt_pad_kernel(
    const float* __restrict__ src, unsigned short* __restrict__ dst,
    int sR, int sC, int dR, int dC) {
  int gid = blockIdx.x * 256 + threadIdx.x;
  int i4 = gid * 4;
  if (i4 >= dR * dC) return;
  int r = i4 / dC;
  int c = i4 - r * dC;
  unsigned short o[4];
#pragma unroll
  for (int j = 0; j < 4; ++j) {
    int cc = c + j;
    float v = (r < sR && cc < sC) ? src[(size_t)r * sC + cc] : 0.f;
    o[j] = f2bf(v);
  }
  unsigned int lo = (unsigned)o[0] | ((unsigned)o[1] << 16);
  unsigned int hi = (unsigned)o[2] | ((unsigned)o[3] << 16);
  *reinterpret_cast<uint2*>(dst + i4) = make_uint2(lo, hi);
}

// ---- transpose + convert: src (K x N) f32 -> dst (N x Kp) bf16, zero pad ----
__global__ __launch_bounds__(256) void transpose_cvt_kernel(
    const float* __restrict__ src, unsigned short* __restrict__ dst,
    int K, int N, int Kp) {
  __shared__ float tl[32][33];
  const int ntk = Kp >> 5;
  int bx = blockIdx.x % ntk;
  int by = blockIdx.x / ntk;
  int k0 = bx * 32, n0 = by * 32;
  int tx = threadIdx.x & 31, ty = threadIdx.x >> 5;
#pragma unroll
  for (int i = 0; i < 4; ++i) {
    int k = k0 + ty + i * 8;
    tl[ty + i * 8][tx] = (k < K) ? src[(size_t)k * N + n0 + tx] : 0.f;
  }
  __syncthreads();
#pragma unroll
  for (int i = 0; i < 4; ++i) {
    int n = n0 + ty + i * 8;
    dst[(size_t)n * Kp + k0 + tx] = f2bf(tl[tx][ty + i * 8]);
  }
}

// ---- float4 zero ----
__global__ __launch_bounds__(256) void zero_kernel(float4* __restrict__ p, int n) {
  int i = blockIdx.x * 256 + threadIdx.x;
  if (i < n) p[i] = make_float4(0.f, 0.f, 0.f, 0.f);
}

// ---- Stream-K 4-phase pipelined GEMM ----
// C(Mout x NB) += A(256-tiled) * Bt^T over unit stream; tile 256x256, BK=64,
// 8 waves (2M x 4N), per-wave 128x64 (MFMA-bound geometry: 24 ds_read vs 64
// MFMA per K-tile per wave). LDS = 8 half-slots x 16KB (A/B x half x parity).
// Per unit u (one K-tile), 4 phases (kk,qn quadrants of the wave tile):
//   P1: vmcnt(4); s_barrier; stage B(u+1); read A-kk0(8)+B01-kk0(2); 16 MFMA
//   P2: read B23-kk0(2); 16 MFMA
//   P3: read A-kk1(8)+B23-kk1(2); 16 MFMA
//   P4: s_barrier; stage A(u+2); read B01-kk1(2); 16 MFMA
// Invariants: A(u) dies at P3 (stage A at P4 targets same-parity slots);
// B(u-1) dies at P4(u-1) (stage B at P1 targets other-parity slots);
// vmcnt(4) at P1 = B(u) landed, A(u+1)'s 4 loads may stay in flight.
// Stream-K: grid=256, block b covers units [b*U/256,(b+1)*U/256); tile
// boundaries flush acc via unsafeAtomicAdd into pre-zeroed C (deterministic
// up to ulp-level add order; threshold has 5x headroom). XCD-contiguous remap.
template <int NKT>
__global__ __launch_bounds__(512) void gemm_sk(
    const unsigned short* __restrict__ Ab,
    const unsigned short* __restrict__ Bt,
    float* __restrict__ C,
    int Kp, int Mout, int total_units) {
  extern __shared__ unsigned short lds[];  // 8 * 8192 shorts = 128 KB
  const int tid = threadIdx.x;
  const int wid = tid >> 6;
  const int lane = tid & 63;
  const int wm = (wid >> 2) << 7;  // 0 / 128
  const int wn = (wid & 3) << 6;   // 0 / 64 / 128 / 192
  // XCD-contiguous work remap: XCD x (= blockIdx%8) gets contiguous range
  const int b = blockIdx.x;
  const int bw = ((b & 7) << 5) | (b >> 3);
  const int s = (int)(((long long)bw * total_units) >> 8);
  const int e = (int)(((long long)(bw + 1) * total_units) >> 8);

  // lane-invariant fragment granules (row&7 == lane&7 for all frags)
  const int g0 = ((lane >> 4) ^ (lane & 7)) * 8;        // kk=0
  const int g1 = ((4 + (lane >> 4)) ^ (lane & 7)) * 8;  // kk=1
  const int alo = (lane & 15) * 64;
  const int bhalf = (wn >> 7) << 1;   // B half-slot pair base
  const int ahalf = (wid >> 2) << 1;  // A half-slot pair base
  const int bsub = ((wn & 64) << 6) + alo;  // B local row offset (shorts)

// stage 4x global_load_lds (2 halves x 2 rounds) for unit UNIT (clamped data,
// pipeline-position parity), matrix ISA(1=A,0=B)
#define STAGE(UNIT, ISA)                                                       \
  do {                                                                         \
    const int rq_ = (UNIT);                                                    \
    const int us_ = rq_ < e - 1 ? rq_ : e - 1;                                 \
    const int par_ = rq_ & 1;                                                  \
    const int tau_ = us_ / NKT;                                                \
    const int kt_ = us_ - tau_ * NKT;                                          \
    const size_t gr_ = (size_t)((ISA) ? (tau_ >> 2) : (tau_ & 3)) << 8;        \
    const unsigned short* M_ = (ISA) ? Ab : Bt;                                \
    _Pragma("unroll")                                                          \
    for (int h_ = 0; h_ < 2; ++h_) {                                           \
      _Pragma("unroll")                                                        \
      for (int L_ = 0; L_ < 2; ++L_) {                                         \
        const int s_ = L_ * 512 + tid;                                         \
        const int row_ = s_ >> 3;                                              \
        const int gl_ = (s_ & 7) ^ (row_ & 7);                                 \
        const unsigned short* g_ = M_ + (gr_ + (h_ << 7) + row_) * (size_t)Kp  \
                                      + (kt_ << 6) + gl_ * 8;                  \
        unsigned short* l_ = lds + (((ISA) ? 0 : 4) + (h_ << 1) + par_) * 8192 \
                                 + (size_t)(L_ * 512 + wid * 64) * 8;          \
        __builtin_amdgcn_global_load_lds(                                      \
            (const __attribute__((address_space(1))) void*)g_,                 \
            (__attribute__((address_space(3))) void*)l_, 16, 0, 0);            \
      }                                                                        \
    }                                                                          \
  } while (0)

#define MFMA16(BV0, BV1, NF0, NF1)                                             \
  do {                                                                         \
    __builtin_amdgcn_s_setprio(1);                                             \
    _Pragma("unroll")                                                          \
    for (int mf_ = 0; mf_ < 8; ++mf_) {                                        \
      asm volatile("v_mfma_f32_16x16x32_bf16 %0, %1, %2, %0"                   \
                   : "+v"(acc[mf_][NF0]) : "v"(af[mf_]), "v"(BV0));            \
      asm volatile("v_mfma_f32_16x16x32_bf16 %0, %1, %2, %0"                   \
                   : "+v"(acc[mf_][NF1]) : "v"(af[mf_]), "v"(BV1));            \
    }                                                                          \
    __builtin_amdgcn_s_setprio(0);                                             \
  } while (0)

#define FLUSH(TAU)                                                             \
  do {                                                                         \
    const int bm_ = (TAU) >> 2, bn_ = (TAU) & 3;                               \
    _Pragma("unroll")                                                          \
    for (int mf_ = 0; mf_ < 8; ++mf_) {                                        \
      const int rb_ = (bm_ << 8) + wm + mf_ * 16 + ((lane >> 4) << 2);         \
      _Pragma("unroll")                                                        \
      for (int nf_ = 0; nf_ < 4; ++nf_) {                                      \
        const int col_ = (bn_ << 8) + wn + nf_ * 16 + (lane & 15);             \
        _Pragma("unroll")                                                      \
        for (int r_ = 0; r_ < 4; ++r_) {                                       \
          const int row_ = rb_ + r_;                                           \
          if (row_ < Mout)                                                     \
            unsafeAtomicAdd(&C[(size_t)row_ * NB + col_], acc[mf_][nf_][r_]);  \
        }                                                                      \
        acc[mf_][nf_] = (f32x4)(0.0f);                                         \
      }                                                                        \
    }                                                                          \
  } while (0)

  f32x4 acc[8][4];
#pragma unroll
  for (int i = 0; i < 8; ++i)
#pragma unroll
    for (int j = 0; j < 4; ++j) acc[i][j] = (f32x4)(0.0f);

  // prologue: A(s), B(s), A(s+1)
  STAGE(s, 1);
  STAGE(s, 0);
  STAGE(s + 1, 1);

  int tau_cur = s / NKT;
  for (int u = s; u < e; ++u) {
    const int par = u & 1;
    const unsigned short* Ab_ = lds + (ahalf + par) * 8192 + alo;
    const unsigned short* Bb_ = lds + (4 + bhalf + par) * 8192 + bsub;
    short8 af[8], b0, b1;
    // ---- P1: publish u; stage B(u+1); (kk0, nf 0-1) ----
    __builtin_amdgcn_sched_barrier(0);
    asm volatile("s_waitcnt vmcnt(4)" ::: "memory");
    __builtin_amdgcn_s_barrier();
    __builtin_amdgcn_sched_barrier(0);
    STAGE(u + 1, 0);
#pragma unroll
    for (int mf = 0; mf < 8; ++mf)
      af[mf] = *reinterpret_cast<const short8*>(Ab_ + mf * 1024 + g0);
    b0 = *reinterpret_cast<const short8*>(Bb_ + 0 * 1024 + g0);
    b1 = *reinterpret_cast<const short8*>(Bb_ + 1 * 1024 + g0);
    MFMA16(b0, b1, 0, 1);
    // ---- P2: (kk0, nf 2-3) ----
    b0 = *reinterpret_cast<const short8*>(Bb_ + 2 * 1024 + g0);
    b1 = *reinterpret_cast<const short8*>(Bb_ + 3 * 1024 + g0);
    MFMA16(b0, b1, 2, 3);
    // ---- P3: (kk1, nf 2-3) ----
#pragma unroll
    for (int mf = 0; mf < 8; ++mf)
      af[mf] = *reinterpret_cast<const short8*>(Ab_ + mf * 1024 + g1);
    b0 = *reinterpret_cast<const short8*>(Bb_ + 2 * 1024 + g1);
    b1 = *reinterpret_cast<const short8*>(Bb_ + 3 * 1024 + g1);
    MFMA16(b0, b1, 2, 3);
    // ---- P4: A(u) dead; stage A(u+2); (kk1, nf 0-1) ----
    __builtin_amdgcn_sched_barrier(0);
    __builtin_amdgcn_s_barrier();
    __builtin_amdgcn_sched_barrier(0);
    STAGE(u + 2, 1);
    b0 = *reinterpret_cast<const short8*>(Bb_ + 0 * 1024 + g1);
    b1 = *reinterpret_cast<const short8*>(Bb_ + 1 * 1024 + g1);
    MFMA16(b0, b1, 0, 1);
    // ---- tile boundary / end: flush partial into C ----
    if (u + 1 >= e) {
      FLUSH(tau_cur);
    } else {
      const int tn = (u + 1) / NKT;
      if (tn != tau_cur) { FLUSH(tau_cur); tau_cur = tn; }
    }
  }
#undef STAGE
#undef MFMA16
#undef FLUSH
}

// ---- conv: z (>=8193 x 1024) f32 -> tT (1024 x KP2) bf16 (transposed t) ----
__global__ __launch_bounds__(256) void conv_tT_kernel(
    const float* __restrict__ z, const float* __restrict__ w,
    const float* __restrict__ bias, unsigned short* __restrict__ tT) {
  const int gid = blockIdx.x * 256 + threadIdx.x;
  const int n = gid & 1023;
  const int rg = gid >> 10;  // 0..519
  const int r0 = rg << 3;
  const float hom = z[(size_t)8192 * 1024 + n];
  unsigned short o[8];
  if (r0 >= 4096) {
#pragma unroll
    for (int j = 0; j < 8; ++j) o[j] = f2bf((r0 + j == 4096) ? hom : 0.f);
  } else {
    const int co = r0 >> 8;
    const int uo = (r0 >> 4) & 15;
    const int vo0 = r0 & 15;  // 0 or 8
    float acc[8];
    const float bb = bias[co];
#pragma unroll
    for (int j = 0; j < 8; ++j) acc[j] = bb * hom;
    for (int ci = 0; ci < 8; ++ci) {
#pragma unroll
      for (int kh = 0; kh < 3; ++kh) {
        const int u = uo * 2 + kh;
        if (u >= 32) continue;
        const float* zbase = z + (size_t)(ci * 1024 + u * 32) * 1024 + n;
#pragma unroll
        for (int kw = 0; kw < 3; ++kw) {
          const float wv = w[((co * 8 + ci) * 3 + kh) * 3 + kw];
#pragma unroll
          for (int j = 0; j < 8; ++j) {
            const int v = (vo0 + j) * 2 + kw;
            if (v < 32) acc[j] += wv * zbase[(size_t)v * 1024];
          }
        }
      }
    }
#pragma unroll
    for (int j = 0; j < 8; ++j) o[j] = f2bf(acc[j]);
  }
  uint4 pv;
  pv.x = (unsigned)o[0] | ((unsigned)o[1] << 16);
  pv.y = (unsigned)o[2] | ((unsigned)o[3] << 16);
  pv.z = (unsigned)o[4] | ((unsigned)o[5] << 16);
  pv.w = (unsigned)o[6] | ((unsigned)o[7] << 16);
  *reinterpret_cast<uint4*>(tT + (size_t)n * KP2 + r0) = pv;
}

extern "C" void kernel_launch(void* const* d_in, const int* in_sizes, int n_in,
                              void* d_out, int out_size, void* d_ws, size_t ws_size,
                              hipStream_t stream) {
  const float* w    = (const float*)d_in[0];  // (16,8,3,3)
  const float* bias = (const float*)d_in[1];  // (16,)
  const float* A    = (const float*)d_in[2];  // (4097,4097)
  const float* Ainv = (const float*)d_in[3];  // (8193,8193)
  const float* x    = (const float*)d_in[4];  // (8193,1024)
  float* out = (float*)d_out;                 // (4097,1024)

  // Workspace (199.5 MB): Ainv_b 139.5 | xT_b 16.9 | z 34.6 | tT_b 8.5
  // A2_b (36.2) aliases Ainv_b (dead after GEMM1; cvt runs after conv).
  char* ws = (char*)d_ws;
  unsigned short* Ainv_b = (unsigned short*)ws;
  unsigned short* xT_b   = (unsigned short*)(ws + (size_t)MP1 * KP1 * 2);
  float*          z      = (float*)(ws + (size_t)MP1 * KP1 * 2 + (size_t)NB * KP1 * 2);
  unsigned short* tT_b   = (unsigned short*)(ws + (size_t)MP1 * KP1 * 2 + (size_t)NB * KP1 * 2
                                             + (size_t)MP1 * NB * 4);
  unsigned short* A2_b   = Ainv_b;
  (void)ws_size; (void)in_sizes; (void)n_in; (void)out_size;

  hipFuncSetAttribute((const void*)gemm_sk<129>,
                      hipFuncAttributeMaxDynamicSharedMemorySize, 131072);
  hipFuncSetAttribute((const void*)gemm_sk<65>,
                      hipFuncAttributeMaxDynamicSharedMemorySize, 131072);

  // 1) Ainv -> padded bf16 (MP1 x KP1)
  cvt_pad_kernel<<<(MP1 * KP1 / 4 + 255) / 256, 256, 0, stream>>>(
      Ainv, Ainv_b, IN_DIM, IN_DIM, MP1, KP1);
  // 2) x -> x^T padded bf16 (NB x KP1)
  transpose_cvt_kernel<<<(KP1 / 32) * (NB / 32), 256, 0, stream>>>(
      x, xT_b, IN_DIM, NB, KP1);
  // 3) zero z (atomic accumulation target)
  zero_kernel<<<(MP1 * NB / 4 + 255) / 256, 256, 0, stream>>>(
      (float4*)z, MP1 * NB / 4);
  // 4) z += Ainv @ x  (stream-K, 33x4 tiles x 129 kt = 17028 units)
  gemm_sk<129><<<256, 512, 131072, stream>>>(
      Ainv_b, xT_b, z, KP1, MP1, 33 * 4 * 129);
  // 5) t^T = conv(z)
  conv_tT_kernel<<<(520 * 1024) / 256, 256, 0, stream>>>(z, w, bias, tT_b);
  // 6) A -> padded bf16 (MP2 x KP2)  [aliases Ainv_b, dead]
  cvt_pad_kernel<<<(MP2 * KP2 / 4 + 255) / 256, 256, 0, stream>>>(
      A, A2_b, OUT_DIM, OUT_DIM, MP2, KP2);
  // 7) zero out; out += A @ t  (stream-K, 17x4 tiles x 65 kt = 4420 units)
  zero_kernel<<<(OUT_DIM * NB / 4 + 255) / 256, 256, 0, stream>>>(
      (float4*)out, OUT_DIM * NB / 4);
  gemm_sk<65><<<256, 512, 131072, stream>>>(
      A2_b, tT_b, out, KP2, OUT_DIM, 17 * 4 * 65);
}